// Round 1
// baseline (528.787 us; speedup 1.0000x reference)
//
#include <hip/hip_runtime.h>
#include <cstdint>
#include <cstddef>

#define BB 64
#define NN 8192
#define MM 128
#define CHUNKS 32          // update: blocks per batch
#define BCH 4              // weight: chunks per batch
#define CELEM (NN / BCH)   // 2048 elements per weight block

typedef float f4 __attribute__((ext_vector_type(4)));

// ---------------- Kernel A: p[b,n] = exp(beta*cos(memory[b,n,:]+eps, k[b]+eps) - beta)
// plus per-batch softmax denominator S[b] via one atomicAdd per wave.
// cos <= 1 so the shift by beta makes exp() safe: values in [e^-10, 1].
// 8192 waves, 128 per batch, 64 consecutive rows per wave; lane float4 loads
// cover 2 rows per wave-load; 5-level butterfly within each 32-lane half.
__global__ __launch_bounds__(256) void score_kernel(const float* __restrict__ memory,
                                                    const float* __restrict__ k,
                                                    const float* __restrict__ beta,
                                                    float* __restrict__ p,
                                                    float* __restrict__ S) {
    const int gw   = (blockIdx.x * 256 + threadIdx.x) >> 6;  // 0..8191
    const int lane = threadIdx.x & 63;
    const int b    = gw >> 7;          // 128 waves per batch
    const int ws   = gw & 127;
    const int l32  = lane & 31;
    const int half = lane >> 5;

    float4 kv = ((const float4*)(k + b * MM))[l32];
    kv.x += 1e-16f; kv.y += 1e-16f; kv.z += 1e-16f; kv.w += 1e-16f;
    float nk2 = kv.x * kv.x + kv.y * kv.y + kv.z * kv.z + kv.w * kv.w;
    #pragma unroll
    for (int o = 1; o < 32; o <<= 1) nk2 += __shfl_xor(nk2, o, 64);
    const float bv = beta[b];
    const float sb = bv / fmaxf(sqrtf(nk2), 1e-8f);

    const int row0 = ws * 64;                       // 64 rows per wave
    const float4* mp = (const float4*)(memory + ((size_t)b * NN + row0) * MM);
    float* pout = p + (size_t)b * NN + row0;

    float ls = 0.f;
    #pragma unroll 2
    for (int it = 0; it < 32; ++it) {               // 2 rows per iteration
        float4 m = mp[it * 64 + lane];
        m.x += 1e-16f; m.y += 1e-16f; m.z += 1e-16f; m.w += 1e-16f;
        float pdot = m.x * kv.x + m.y * kv.y + m.z * kv.z + m.w * kv.w;
        float pnm  = m.x * m.x + m.y * m.y + m.z * m.z + m.w * m.w;
        #pragma unroll
        for (int o = 1; o < 32; o <<= 1) {
            pdot += __shfl_xor(pdot, o, 64);
            pnm  += __shfl_xor(pnm,  o, 64);
        }
        if (l32 == 0) {
            const float pe = __expf(sb * pdot / fmaxf(sqrtf(pnm), 1e-8f) - bv);
            pout[it * 2 + half] = pe;
            ls += pe;
        }
    }
    ls += __shfl_xor(ls, 32, 64);                   // combine lane 0 + lane 32 partials
    if (lane == 0) atomicAdd(S + b, ls);
}

// ---------------- Kernel B: interpolation + circular shift + sharpen + per-batch sum T[b].
// Fully parallel: 256 blocks (4 per batch), one barrier, one atomic per block.
// Final 1/(T+eps) normalization is folded into the update kernel.
__global__ __launch_bounds__(256) void weight_kernel(const float* __restrict__ p,
                                                     const float* __restrict__ S,
                                                     const float* __restrict__ g,
                                                     const float* __restrict__ s,
                                                     const float* __restrict__ gamma,
                                                     const float* __restrict__ w_prev,
                                                     float* __restrict__ t,
                                                     float* __restrict__ T) {
    __shared__ float wgs[CELEM + 2];
    __shared__ float red[4];
    const int b   = blockIdx.x >> 2;
    const int c0  = (blockIdx.x & 3) * CELEM;
    const int tid = threadIdx.x;

    const float invS = 1.f / S[b];
    const float gv = g[b], omg = 1.f - gv;
    const float* pb = p + (size_t)b * NN;
    const float* wp = w_prev + (size_t)b * NN;
    #pragma unroll
    for (int j = 0; j < CELEM / 256; j++) {
        const int i = tid + j * 256;
        wgs[1 + i] = gv * (pb[c0 + i] * invS) + omg * wp[c0 + i];
    }
    if (tid == 0) {
        const int im = (c0 - 1) & (NN - 1);          // circular halo left
        wgs[0] = gv * (pb[im] * invS) + omg * wp[im];
    } else if (tid == 1) {
        const int ip = (c0 + CELEM) & (NN - 1);      // circular halo right
        wgs[CELEM + 1] = gv * (pb[ip] * invS) + omg * wp[ip];
    }
    __syncthreads();

    const float s0 = s[b * 3 + 0], s1 = s[b * 3 + 1], s2 = s[b * 3 + 2];
    const float gam = gamma[b];
    float lsum = 0.f;
    float* tb = t + (size_t)b * NN + c0;
    #pragma unroll
    for (int j = 0; j < CELEM / 256; j++) {
        const int i = tid + j * 256;
        const float wh = s0 * wgs[i] + s1 * wgs[i + 1] + s2 * wgs[i + 2];
        const float tv = __expf(gam * __logf(wh));   // wh > 0 guaranteed
        tb[i] = tv;
        lsum += tv;
    }
    #pragma unroll
    for (int o = 32; o > 0; o >>= 1) lsum += __shfl_xor(lsum, o, 64);
    if ((tid & 63) == 0) red[tid >> 6] = lsum;
    __syncthreads();
    if (tid == 0) atomicAdd(T + b, red[0] + red[1] + red[2] + red[3]);
}

// ---------------- Kernel C: r[b,m] = sum_n w*mem ; new_mem = mem*(1 - w*e) + w*a
// w = t * 1/(T+eps) folded in. REVERSE traversal order: score read memory
// ascending, so its tail is L3-resident; reading it first turns update's
// fetches into Infinity-Cache hits. Non-temporal loads (no reuse after this)
// and non-temporal stores (never read) keep the resident tail from being evicted.
__global__ __launch_bounds__(256) void update_kernel(const float* __restrict__ memory,
                                                     const float* __restrict__ t,
                                                     const float* __restrict__ T,
                                                     const float* __restrict__ e,
                                                     const float* __restrict__ a,
                                                     float* __restrict__ r,
                                                     float* __restrict__ nmem) {
    const int rev   = (BB * CHUNKS - 1) - (int)blockIdx.x;
    const int b     = rev / CHUNKS;
    const int chunk = rev % CHUNKS;
    const int rows  = NN / CHUNKS;          // 256
    const int n0    = chunk * rows;
    const int tid   = threadIdx.x;
    const int c4    = tid & 31;             // float4 column group
    const int rg    = tid >> 5;             // row offset within group of 8

    const f4 e4 = ((const f4*)(e + b * MM))[c4];
    const f4 a4 = ((const f4*)(a + b * MM))[c4];
    const float invT = 1.f / (T[b] + 1e-16f);
    const float* wb = t + (size_t)b * NN + n0;
    const size_t base = ((size_t)b * NN + n0) * MM;
    const f4* min4 = (const f4*)(memory + base);
    f4* mout4      = (f4*)(nmem + base);

    f4 acc = {0.f, 0.f, 0.f, 0.f};
    #pragma unroll 2
    for (int it = 0; it < rows; it += 8) {
        const int rr = it + rg;
        const float wv = wb[rr] * invT;
        const int idx = rr * 32 + c4;
        const f4 m4 = __builtin_nontemporal_load(min4 + idx);
        acc += wv * m4;
        f4 o4 = m4 * (1.f - wv * e4) + wv * a4;
        __builtin_nontemporal_store(o4, mout4 + idx);
    }

    __shared__ f4 sred[256];
    sred[tid] = acc;
    __syncthreads();
    if (tid < 32) {
        f4 tt = sred[tid];
        #pragma unroll
        for (int j = 1; j < 8; j++) tt += sred[tid + j * 32];
        float* rp = r + b * MM + tid * 4;
        atomicAdd(rp + 0, tt.x);
        atomicAdd(rp + 1, tt.y);
        atomicAdd(rp + 2, tt.z);
        atomicAdd(rp + 3, tt.w);
    }
}

extern "C" void kernel_launch(void* const* d_in, const int* in_sizes, int n_in,
                              void* d_out, int out_size, void* d_ws, size_t ws_size,
                              hipStream_t stream) {
    const float* memory = (const float*)d_in[0];
    const float* k      = (const float*)d_in[1];
    const float* beta   = (const float*)d_in[2];
    const float* g      = (const float*)d_in[3];
    const float* s      = (const float*)d_in[4];
    const float* gamma  = (const float*)d_in[5];
    const float* w_prev = (const float*)d_in[6];
    const float* e      = (const float*)d_in[7];
    const float* a      = (const float*)d_in[8];

    float* out  = (float*)d_out;
    float* r    = out;                       // [B, M]
    float* nmem = out + BB * MM;             // [B, N, M]

    float* p  = (float*)d_ws;                // [B, N] exp(logit - beta)
    float* t  = p + (size_t)BB * NN;         // [B, N] w_hat^gamma (unnormalized)
    float* S  = t + (size_t)BB * NN;         // [B] softmax denominator
    float* T  = S + BB;                      // [B] sharpen denominator

    hipMemsetAsync(r, 0, BB * MM * sizeof(float), stream);
    hipMemsetAsync(S, 0, 2 * BB * sizeof(float), stream);

    score_kernel<<<2048, 256, 0, stream>>>(memory, k, beta, p, S);
    weight_kernel<<<BB * BCH, 256, 0, stream>>>(p, S, g, s, gamma, w_prev, t, T);
    update_kernel<<<BB * CHUNKS, 256, 0, stream>>>(memory, t, T, e, a, r, nmem);
}

// Round 2
// 498.939 us; speedup vs baseline: 1.0598x; 1.0598x over previous
//
#include <hip/hip_runtime.h>
#include <cstdint>
#include <cstddef>

#define BB 64
#define NN 8192
#define MM 128
#define CHUNKS 32          // update: blocks per batch
#define BCH 4              // weight: chunks per batch
#define CELEM (NN / BCH)   // 2048 elements per weight block

typedef float f4 __attribute__((ext_vector_type(4)));

// ---------------- Kernel A: p[b,n] = exp(beta*cos(memory[b,n,:]+eps, k[b]+eps) - beta)
// Per-wave partial softmax denominators written to Sp[b*128+ws] (no atomics, no memset).
// cos <= 1 so the beta shift keeps exp() in [e^-10, 1] -- no max pass needed.
__global__ __launch_bounds__(256) void score_kernel(const float* __restrict__ memory,
                                                    const float* __restrict__ k,
                                                    const float* __restrict__ beta,
                                                    float* __restrict__ p,
                                                    float* __restrict__ Sp) {
    const int gw   = (blockIdx.x * 256 + threadIdx.x) >> 6;  // 0..8191
    const int lane = threadIdx.x & 63;
    const int b    = gw >> 7;          // 128 waves per batch
    const int ws   = gw & 127;
    const int l32  = lane & 31;
    const int half = lane >> 5;

    float4 kv = ((const float4*)(k + b * MM))[l32];
    kv.x += 1e-16f; kv.y += 1e-16f; kv.z += 1e-16f; kv.w += 1e-16f;
    float nk2 = kv.x * kv.x + kv.y * kv.y + kv.z * kv.z + kv.w * kv.w;
    #pragma unroll
    for (int o = 1; o < 32; o <<= 1) nk2 += __shfl_xor(nk2, o, 64);
    const float bv = beta[b];
    const float sb = bv / fmaxf(sqrtf(nk2), 1e-8f);

    const int row0 = ws * 64;                       // 64 rows per wave
    const float4* mp = (const float4*)(memory + ((size_t)b * NN + row0) * MM);
    float* pout = p + (size_t)b * NN + row0;

    float ls = 0.f;
    #pragma unroll 2
    for (int it = 0; it < 32; ++it) {               // 2 rows per iteration
        float4 m = mp[it * 64 + lane];
        m.x += 1e-16f; m.y += 1e-16f; m.z += 1e-16f; m.w += 1e-16f;
        float pdot = m.x * kv.x + m.y * kv.y + m.z * kv.z + m.w * kv.w;
        float pnm  = m.x * m.x + m.y * m.y + m.z * m.z + m.w * m.w;
        #pragma unroll
        for (int o = 1; o < 32; o <<= 1) {
            pdot += __shfl_xor(pdot, o, 64);
            pnm  += __shfl_xor(pnm,  o, 64);
        }
        if (l32 == 0) {
            const float pe = __expf(sb * pdot / fmaxf(sqrtf(pnm), 1e-8f) - bv);
            pout[it * 2 + half] = pe;
            ls += pe;
        }
    }
    ls += __shfl_xor(ls, 32, 64);                   // lane0 += lane32 partial
    if (lane == 0) Sp[(b << 7) + ws] = ls;
}

// ---------------- Kernel B: interpolation + circular shift + sharpen.
// Reduces Sp -> invS locally; writes per-block sharpen partial Tp[b*4+c] (no atomics).
__global__ __launch_bounds__(256) void weight_kernel(const float* __restrict__ p,
                                                     const float* __restrict__ Sp,
                                                     const float* __restrict__ g,
                                                     const float* __restrict__ s,
                                                     const float* __restrict__ gamma,
                                                     const float* __restrict__ w_prev,
                                                     float* __restrict__ t,
                                                     float* __restrict__ Tp) {
    __shared__ float wgs[CELEM + 2];
    __shared__ float red[4];
    const int b    = blockIdx.x >> 2;
    const int cidx = blockIdx.x & 3;
    const int c0   = cidx * CELEM;
    const int tid  = threadIdx.x;

    // --- reduce the 128 per-wave softmax partials (redundantly per block) ---
    float sv = (tid < 128) ? Sp[(b << 7) + tid] : 0.f;
    #pragma unroll
    for (int o = 32; o > 0; o >>= 1) sv += __shfl_xor(sv, o, 64);
    if ((tid & 63) == 0) red[tid >> 6] = sv;
    __syncthreads();
    const float invS = 1.f / (red[0] + red[1]);

    const float gv = g[b], omg = 1.f - gv;
    const float* pb = p + (size_t)b * NN;
    const float* wp = w_prev + (size_t)b * NN;
    #pragma unroll
    for (int j = 0; j < CELEM / 256; j++) {
        const int i = tid + j * 256;
        wgs[1 + i] = gv * (pb[c0 + i] * invS) + omg * wp[c0 + i];
    }
    if (tid == 0) {
        const int im = (c0 - 1) & (NN - 1);          // circular halo left
        wgs[0] = gv * (pb[im] * invS) + omg * wp[im];
    } else if (tid == 1) {
        const int ip = (c0 + CELEM) & (NN - 1);      // circular halo right
        wgs[CELEM + 1] = gv * (pb[ip] * invS) + omg * wp[ip];
    }
    __syncthreads();

    const float s0 = s[b * 3 + 0], s1 = s[b * 3 + 1], s2 = s[b * 3 + 2];
    const float gam = gamma[b];
    float lsum = 0.f;
    float* tb = t + (size_t)b * NN + c0;
    #pragma unroll
    for (int j = 0; j < CELEM / 256; j++) {
        const int i = tid + j * 256;
        const float wh = s0 * wgs[i] + s1 * wgs[i + 1] + s2 * wgs[i + 2];
        const float tv = __expf(gam * __logf(wh));   // wh > 0 guaranteed
        tb[i] = tv;
        lsum += tv;
    }
    #pragma unroll
    for (int o = 32; o > 0; o >>= 1) lsum += __shfl_xor(lsum, o, 64);
    __syncthreads();                                  // red reuse
    if ((tid & 63) == 0) red[tid >> 6] = lsum;
    __syncthreads();
    if (tid == 0) Tp[b * 4 + cidx] = red[0] + red[1] + red[2] + red[3];
}

// ---------------- Kernel C: r[b,m] = sum_n w*mem ; new_mem = mem*(1 - w*e) + w*a
// w = t/(T+eps) folded in. REVERSE traversal: score read memory ascending, so
// its tail is Infinity-Cache resident; reading it first turns these fetches into
// L3 hits. PLAIN loads (must be allowed to hit/allocate in L3 -- NT loads were
// the round-1 mistake). NT stores only: nmem is never re-read, and no-allocate
// stores keep nmem from evicting the still-unread memory tail.
__global__ __launch_bounds__(256) void update_kernel(const float* __restrict__ memory,
                                                     const float* __restrict__ t,
                                                     const float* __restrict__ Tp,
                                                     const float* __restrict__ e,
                                                     const float* __restrict__ a,
                                                     float* __restrict__ r,
                                                     float* __restrict__ nmem) {
    const int rev   = (BB * CHUNKS - 1) - (int)blockIdx.x;
    const int b     = rev / CHUNKS;
    const int chunk = rev % CHUNKS;
    const int rows  = NN / CHUNKS;          // 256
    const int n0    = chunk * rows;
    const int tid   = threadIdx.x;
    const int c4    = tid & 31;             // float4 column group
    const int rg    = tid >> 5;             // row offset within group of 8

    const f4 e4 = ((const f4*)(e + b * MM))[c4];
    const f4 a4 = ((const f4*)(a + b * MM))[c4];
    const float Tb = Tp[b * 4 + 0] + Tp[b * 4 + 1] + Tp[b * 4 + 2] + Tp[b * 4 + 3];
    const float invT = 1.f / (Tb + 1e-16f);
    const float* wb = t + (size_t)b * NN + n0;
    const size_t base = ((size_t)b * NN + n0) * MM;
    const f4* min4 = (const f4*)(memory + base);
    f4* mout4      = (f4*)(nmem + base);

    f4 acc = {0.f, 0.f, 0.f, 0.f};
    #pragma unroll 4
    for (int it = 0; it < rows; it += 8) {
        const int rr = it + rg;
        const float wv = wb[rr] * invT;
        const int idx = rr * 32 + c4;
        const f4 m4 = min4[idx];
        acc += wv * m4;
        f4 o4 = m4 * (1.f - wv * e4) + wv * a4;
        __builtin_nontemporal_store(o4, mout4 + idx);
    }

    __shared__ f4 sred[256];
    sred[tid] = acc;
    __syncthreads();
    if (tid < 32) {
        f4 tt = sred[tid];
        #pragma unroll
        for (int j = 1; j < 8; j++) tt += sred[tid + j * 32];
        float* rp = r + b * MM + tid * 4;
        atomicAdd(rp + 0, tt.x);
        atomicAdd(rp + 1, tt.y);
        atomicAdd(rp + 2, tt.z);
        atomicAdd(rp + 3, tt.w);
    }
}

extern "C" void kernel_launch(void* const* d_in, const int* in_sizes, int n_in,
                              void* d_out, int out_size, void* d_ws, size_t ws_size,
                              hipStream_t stream) {
    const float* memory = (const float*)d_in[0];
    const float* k      = (const float*)d_in[1];
    const float* beta   = (const float*)d_in[2];
    const float* g      = (const float*)d_in[3];
    const float* s      = (const float*)d_in[4];
    const float* gamma  = (const float*)d_in[5];
    const float* w_prev = (const float*)d_in[6];
    const float* e      = (const float*)d_in[7];
    const float* a      = (const float*)d_in[8];

    float* out  = (float*)d_out;
    float* r    = out;                       // [B, M]
    float* nmem = out + BB * MM;             // [B, N, M]

    float* p  = (float*)d_ws;                // [B, N] exp(logit - beta)
    float* t  = p + (size_t)BB * NN;         // [B, N] w_hat^gamma (unnormalized)
    float* Sp = t + (size_t)BB * NN;         // [B, 128] per-wave softmax partials
    float* Tp = Sp + (size_t)BB * 128;       // [B, 4]  per-block sharpen partials

    hipMemsetAsync(r, 0, BB * MM * sizeof(float), stream);
    score_kernel<<<2048, 256, 0, stream>>>(memory, k, beta, p, Sp);
    weight_kernel<<<BB * BCH, 256, 0, stream>>>(p, Sp, g, s, gamma, w_prev, t, Tp);
    update_kernel<<<BB * CHUNKS, 256, 0, stream>>>(memory, t, Tp, e, a, r, nmem);
}